// Round 3
// baseline (3094.021 us; speedup 1.0000x reference)
//
#include <hip/hip_runtime.h>
#include <hip/hip_fp16.h>

// GRUPK: 2-layer GRU, B=256 S=1024 IN+META=8 H=256 G=768, out = last_h2 @ fcW + fcb
//
// 3-phase chunked design (8 chunks x 128 steps):
//   phaseA: layer-0 recurrence. 1 block/batch, W_hh0 resident in VGPRs (128 half2/thread),
//           fp32 accumulate via v_dot2_f32_f16, h-state f16 in LDS (broadcast reads).
//   phaseB: xg1 = h0_chunk @ W_ih1^T + b_ih1 as MFMA f16 GEMM (16x16x32), 128x128 tiles, BK=64.
//   phaseC: layer-1 recurrence (W_hh1 in VGPRs), reads xg1 stream; last chunk writes FC output.
//
// R2 post-mortem: launch_bounds(768,3) only CAPS occupancy demand; compiler still chose
// VGPR=84 (6 waves/EU target) and rematerialized ~half the weight array from L2 every step
// (6.8 GB/dispatch at L2 ~34.5 TB/s = 198 us, matching measured 208 us; VALUBusy 54%).
// R3 fix: amdgpu_waves_per_eu(3,3) pins the allocator to exactly 3 waves/EU -> 170-VGPR
// budget -> the 128-half2 weight row stays fully register-resident. Grid is 1 block/CU
// (256 blocks) so pinned occupancy costs nothing.

#define B_ 256
#define S_ 1024
#define H_ 256
#define G_ 768
#define CHUNK 128
#define NCHUNK (S_ / CHUNK)

typedef _Float16 half8 __attribute__((ext_vector_type(8)));
typedef _Float16 half2_t __attribute__((ext_vector_type(2)));
typedef float f32x4 __attribute__((ext_vector_type(4)));

__device__ __forceinline__ float sigf(float v) {
    return 1.f / (1.f + __expf(-v));
}
__device__ __forceinline__ float tanh_(float v) {
    float a = fabsf(v);
    float e = __expf(-2.f * a);
    float r = (1.f - e) / (1.f + e);
    return copysignf(r, v);
}

__device__ __forceinline__ float dot2acc(half2_t w, half2_t h, float acc) {
#if __has_builtin(__builtin_amdgcn_fdot2)
    return __builtin_amdgcn_fdot2(w, h, acc, false);
#else
    return acc + (float)w[0] * (float)h[0] + (float)w[1] * (float)h[1];
#endif
}

// ---------------- prep: convert weights to f16 layouts ----------------
__global__ void prep_kernel(const float* __restrict__ Whh0,
                            const float* __restrict__ Wih1,
                            const float* __restrict__ Whh1,
                            __half2* __restrict__ WpA,
                            __half* __restrict__ Wi1f,
                            __half2* __restrict__ WpC) {
    int tid = blockIdx.x * 256 + threadIdx.x;  // 768*256 = 196608 threads
    if (tid < 98304) {                          // 128 k-pairs x 768 rows
        int row = tid % G_;
        int k2  = tid / G_;
        WpA[tid] = __floats2half2_rn(Whh0[row * H_ + 2 * k2], Whh0[row * H_ + 2 * k2 + 1]);
        WpC[tid] = __floats2half2_rn(Whh1[row * H_ + 2 * k2], Whh1[row * H_ + 2 * k2 + 1]);
    }
    Wi1f[tid] = __float2half(Wih1[tid]);        // 768*256 straight convert
}

// ---------------- phase A: layer-0 recurrence ----------------
__global__ __launch_bounds__(768, 3)
__attribute__((amdgpu_waves_per_eu(3, 3)))
void phaseA_kernel(
    const float* __restrict__ x, const float* __restrict__ meta,
    const float* __restrict__ Wih0, const float* __restrict__ bih0,
    const float* __restrict__ bhh0, const half2_t* __restrict__ WpA,
    float* __restrict__ h0state, __half* __restrict__ h0chunk, int chunk) {
    const int b = blockIdx.x, t = threadIdx.x;
    __shared__ float  s_hf[H_];   // fp32 h state
    __shared__ __half s_hh[H_];   // f16 copy for the dot
    __shared__ float  s_xg[G_], s_hg[G_];

    // resident weights: row t of W_hh0, 128 k-pairs
    half2_t w[128];
#pragma unroll
    for (int k2 = 0; k2 < 128; k2++) w[k2] = WpA[k2 * G_ + t];

    float wi0[8];
#pragma unroll
    for (int f = 0; f < 8; f++) wi0[f] = Wih0[t * 8 + f];
    const float bi = bih0[t], bh = bhh0[t];
    const float4 mv = reinterpret_cast<const float4*>(meta)[b];

    if (t < H_) {
        float h0 = (chunk == 0) ? 0.f : h0state[b * H_ + t];
        s_hf[t] = h0;
        s_hh[t] = __float2half(h0);
    }
    __syncthreads();

    const float4* xrow = reinterpret_cast<const float4*>(x) + (size_t)b * S_ + (size_t)chunk * CHUNK;

    for (int s = 0; s < CHUNK; s++) {
        float4 xv = xrow[s];  // uniform (broadcast) load
        float a0 = bh, a1 = 0.f, a2 = 0.f, a3 = 0.f;
        const half2_t* hh2 = reinterpret_cast<const half2_t*>(s_hh);
#pragma unroll
        for (int k2 = 0; k2 < 128; k2 += 4) {
            a0 = dot2acc(w[k2 + 0], hh2[k2 + 0], a0);
            a1 = dot2acc(w[k2 + 1], hh2[k2 + 1], a1);
            a2 = dot2acc(w[k2 + 2], hh2[k2 + 2], a2);
            a3 = dot2acc(w[k2 + 3], hh2[k2 + 3], a3);
        }
        float hg = (a0 + a1) + (a2 + a3);
        float xg = bi + xv.x * wi0[0] + xv.y * wi0[1] + xv.z * wi0[2] + xv.w * wi0[3]
                      + mv.x * wi0[4] + mv.y * wi0[5] + mv.z * wi0[6] + mv.w * wi0[7];
        s_xg[t] = xg;
        s_hg[t] = hg;
        __syncthreads();
        if (t < H_) {
            float r  = sigf(s_xg[t] + s_hg[t]);
            float z  = sigf(s_xg[t + H_] + s_hg[t + H_]);
            float n  = tanh_(s_xg[t + 2 * H_] + r * s_hg[t + 2 * H_]);
            float hn = (1.f - z) * n + z * s_hf[t];
            s_hf[t] = hn;
            __half hh = __float2half(hn);
            s_hh[t] = hh;
            h0chunk[((size_t)(s * B_ + b)) * H_ + t] = hh;  // [s][b][j]
        }
        __syncthreads();
    }
    if (t < H_) h0state[b * H_ + t] = s_hf[t];
}

// ---------------- phase B: xg1 = h0_chunk @ W_ih1^T + b_ih1 (MFMA f16) ----------------
__global__ __launch_bounds__(256) void phaseB_kernel(
    const _Float16* __restrict__ h0chunk, const _Float16* __restrict__ Wi1f,
    const float* __restrict__ bih1, __half* __restrict__ xg1chunk) {
    __shared__ _Float16 lA[128 * 72];  // 128 rows x 64 K, +8 pad (16B-aligned rows)
    __shared__ _Float16 lB[128 * 72];
    const int tid = threadIdx.x;
    const int m0 = blockIdx.x * 128, n0 = blockIdx.y * 128;
    const int wid = tid >> 6, lane = tid & 63;
    const int lm = lane & 15, q8 = (lane >> 4) * 8;
    const int rm = (wid & 1) * 64, cn = (wid >> 1) * 64;

    f32x4 acc[4][4] = {};

    const _Float16* Ag = h0chunk + (size_t)m0 * H_;
    const _Float16* Bg = Wi1f + (size_t)n0 * H_;

    for (int ks = 0; ks < 4; ks++) {  // K = 4 x 64
#pragma unroll
        for (int i = 0; i < 4; i++) {
            int lin = i * 256 + tid;  // 1024 chunks of 16B: 128 rows x 8
            int row = lin >> 3, c8 = lin & 7;
            *reinterpret_cast<float4*>(lA + row * 72 + c8 * 8) =
                *reinterpret_cast<const float4*>(Ag + (size_t)row * H_ + ks * 64 + c8 * 8);
            *reinterpret_cast<float4*>(lB + row * 72 + c8 * 8) =
                *reinterpret_cast<const float4*>(Bg + (size_t)row * H_ + ks * 64 + c8 * 8);
        }
        __syncthreads();
#pragma unroll
        for (int kk = 0; kk < 2; kk++) {
            half8 af[4], bf[4];
#pragma unroll
            for (int i = 0; i < 4; i++)
                af[i] = *reinterpret_cast<const half8*>(lA + (rm + i * 16 + lm) * 72 + kk * 32 + q8);
#pragma unroll
            for (int j = 0; j < 4; j++)
                bf[j] = *reinterpret_cast<const half8*>(lB + (cn + j * 16 + lm) * 72 + kk * 32 + q8);
#pragma unroll
            for (int i = 0; i < 4; i++)
#pragma unroll
                for (int j = 0; j < 4; j++)
                    acc[i][j] = __builtin_amdgcn_mfma_f32_16x16x32_f16(af[i], bf[j], acc[i][j], 0, 0, 0);
        }
        __syncthreads();
    }

    // epilogue: D row=(lane>>4)*4+r (M), col=lane&15 (N)
#pragma unroll
    for (int j = 0; j < 4; j++) {
        int n = n0 + cn + j * 16 + lm;
        float bias = bih1[n];
#pragma unroll
        for (int i = 0; i < 4; i++) {
            int mbase = m0 + rm + i * 16 + (lane >> 4) * 4;
#pragma unroll
            for (int r = 0; r < 4; r++) {
                xg1chunk[(size_t)(mbase + r) * G_ + n] = __float2half(acc[i][j][r] + bias);
            }
        }
    }
}

// ---------------- phase C: layer-1 recurrence + final FC ----------------
__global__ __launch_bounds__(768, 3)
__attribute__((amdgpu_waves_per_eu(3, 3)))
void phaseC_kernel(
    const __half* __restrict__ xg1chunk, const half2_t* __restrict__ WpC,
    const float* __restrict__ bhh1, const float* __restrict__ fcW,
    const float* __restrict__ fcb, float* __restrict__ h1state,
    float* __restrict__ out, int chunk) {
    const int b = blockIdx.x, t = threadIdx.x;
    __shared__ float  s_hf[H_];
    __shared__ __half s_hh[H_];
    __shared__ float  s_xg[G_], s_hg[G_];

    half2_t w[128];
#pragma unroll
    for (int k2 = 0; k2 < 128; k2++) w[k2] = WpC[k2 * G_ + t];
    const float bh = bhh1[t];

    if (t < H_) {
        float h0 = (chunk == 0) ? 0.f : h1state[b * H_ + t];
        s_hf[t] = h0;
        s_hh[t] = __float2half(h0);
    }
    __syncthreads();

    for (int s = 0; s < CHUNK; s++) {
        float a0 = bh, a1 = 0.f, a2 = 0.f, a3 = 0.f;
        const half2_t* hh2 = reinterpret_cast<const half2_t*>(s_hh);
#pragma unroll
        for (int k2 = 0; k2 < 128; k2 += 4) {
            a0 = dot2acc(w[k2 + 0], hh2[k2 + 0], a0);
            a1 = dot2acc(w[k2 + 1], hh2[k2 + 1], a1);
            a2 = dot2acc(w[k2 + 2], hh2[k2 + 2], a2);
            a3 = dot2acc(w[k2 + 3], hh2[k2 + 3], a3);
        }
        float hg = (a0 + a1) + (a2 + a3);
        float xg = __half2float(xg1chunk[((size_t)(s * B_ + b)) * G_ + t]);  // b_ih1 pre-added
        s_xg[t] = xg;
        s_hg[t] = hg;
        __syncthreads();
        if (t < H_) {
            float r  = sigf(s_xg[t] + s_hg[t]);
            float z  = sigf(s_xg[t + H_] + s_hg[t + H_]);
            float n  = tanh_(s_xg[t + 2 * H_] + r * s_hg[t + 2 * H_]);
            float hn = (1.f - z) * n + z * s_hf[t];
            s_hf[t] = hn;
            s_hh[t] = __float2half(hn);
        }
        __syncthreads();
    }
    if (t < H_) h1state[b * H_ + t] = s_hf[t];

    if (chunk == NCHUNK - 1) {
        if (t < H_) s_xg[t] = s_hf[t] * fcW[t];
        __syncthreads();
        if (t < 32) {
            float a = 0.f;
            for (int j = t; j < H_; j += 32) a += s_xg[j];
            s_hg[t] = a;
        }
        __syncthreads();
        if (t == 0) {
            float a = fcb[0];
            for (int j = 0; j < 32; j++) a += s_hg[j];
            out[b] = a;
        }
    }
}

extern "C" void kernel_launch(void* const* d_in, const int* in_sizes, int n_in,
                              void* d_out, int out_size, void* d_ws, size_t ws_size,
                              hipStream_t stream) {
    const float* x    = (const float*)d_in[0];
    const float* meta = (const float*)d_in[1];
    const float* Wih0 = (const float*)d_in[2];
    const float* Whh0 = (const float*)d_in[3];
    const float* bih0 = (const float*)d_in[4];
    const float* bhh0 = (const float*)d_in[5];
    const float* Wih1 = (const float*)d_in[6];
    const float* Whh1 = (const float*)d_in[7];
    const float* bih1 = (const float*)d_in[8];
    const float* bhh1 = (const float*)d_in[9];
    const float* fcW  = (const float*)d_in[10];
    const float* fcb  = (const float*)d_in[11];
    float* out = (float*)d_out;

    char* ws = (char*)d_ws;
    __half2* WpA     = (__half2*)(ws + 0);
    __half*  Wi1f    = (__half*)(ws + 393216);
    __half2* WpC     = (__half2*)(ws + 786432);
    float*   h0state = (float*)(ws + 1179648);
    float*   h1state = (float*)(ws + 1441792);
    __half*  h0chunk = (__half*)(ws + 1703936);
    __half*  xg1chunk= (__half*)(ws + 18481152);

    prep_kernel<<<768, 256, 0, stream>>>(Whh0, Wih1, Whh1, WpA, Wi1f, WpC);

    for (int c = 0; c < NCHUNK; c++) {
        phaseA_kernel<<<256, 768, 0, stream>>>(x, meta, Wih0, bih0, bhh0,
                                               (const half2_t*)WpA, h0state, h0chunk, c);
        phaseB_kernel<<<dim3(256, 6), 256, 0, stream>>>(
            (const _Float16*)h0chunk, (const _Float16*)Wi1f, bih1, xg1chunk);
        phaseC_kernel<<<256, 768, 0, stream>>>(xg1chunk, (const half2_t*)WpC, bhh1, fcW, fcb,
                                               h1state, out, c);
    }
}

// Round 4
// 3077.973 us; speedup vs baseline: 1.0052x; 1.0052x over previous
//
#include <hip/hip_runtime.h>
#include <hip/hip_fp16.h>

// GRUPK: 2-layer GRU, B=256 S=1024 IN+META=8 H=256 G=768, out = last_h2 @ fcW + fcb
//
// 3-phase chunked design (8 chunks x 128 steps):
//   phaseA: layer-0 recurrence. 1 block/batch, W_hh0 resident in VGPRs (128 half2/thread),
//           fp32 accumulate via v_dot2_f32_f16, h-state f16 in LDS (b128 broadcast reads).
//   phaseB: xg1 = h0_chunk @ W_ih1^T + b_ih1 as MFMA f16 GEMM (16x16x32), 128x128 tiles, BK=64.
//   phaseC: layer-1 recurrence (W_hh1 in VGPRs), reads xg1 stream; last chunk writes FC output.
//
// R3 post-mortem: __launch_bounds__(768,3) expands to amdgpu_waves_per_eu(3) (min only);
// the extra amdgpu_waves_per_eu(3,3) attribute conflicted and was dropped -> compiler kept
// VGPR=84 and parked the weight array in AGPRs (84+86=170 = exactly 3 waves/EU, matching
// OccupancyPercent 33%), paying a v_accvgpr_read per weight use (2x VALU) -> 208 us.
// R4: pin with amdgpu_flat_work_group_size(768,768) + amdgpu_waves_per_eu(3,3) ONLY
// (no __launch_bounds__), and vectorize h reads as ds_read_b128 broadcast (32/step vs 128).

#define B_ 256
#define S_ 1024
#define H_ 256
#define G_ 768
#define CHUNK 128
#define NCHUNK (S_ / CHUNK)

typedef _Float16 half8 __attribute__((ext_vector_type(8)));
typedef _Float16 half2_t __attribute__((ext_vector_type(2)));
typedef float f32x4 __attribute__((ext_vector_type(4)));

__device__ __forceinline__ float sigf(float v) {
    return 1.f / (1.f + __expf(-v));
}
__device__ __forceinline__ float tanh_(float v) {
    float a = fabsf(v);
    float e = __expf(-2.f * a);
    float r = (1.f - e) / (1.f + e);
    return copysignf(r, v);
}

__device__ __forceinline__ float dot2acc(half2_t w, half2_t h, float acc) {
#if __has_builtin(__builtin_amdgcn_fdot2)
    return __builtin_amdgcn_fdot2(w, h, acc, false);
#else
    return acc + (float)w[0] * (float)h[0] + (float)w[1] * (float)h[1];
#endif
}

__device__ __forceinline__ half2_t h2cast(float v) {
    return __builtin_bit_cast(half2_t, v);
}

// ---------------- prep: convert weights to f16 layouts ----------------
__global__ void prep_kernel(const float* __restrict__ Whh0,
                            const float* __restrict__ Wih1,
                            const float* __restrict__ Whh1,
                            __half2* __restrict__ WpA,
                            __half* __restrict__ Wi1f,
                            __half2* __restrict__ WpC) {
    int tid = blockIdx.x * 256 + threadIdx.x;  // 768*256 = 196608 threads
    if (tid < 98304) {                          // 128 k-pairs x 768 rows
        int row = tid % G_;
        int k2  = tid / G_;
        WpA[tid] = __floats2half2_rn(Whh0[row * H_ + 2 * k2], Whh0[row * H_ + 2 * k2 + 1]);
        WpC[tid] = __floats2half2_rn(Whh1[row * H_ + 2 * k2], Whh1[row * H_ + 2 * k2 + 1]);
    }
    Wi1f[tid] = __float2half(Wih1[tid]);        // 768*256 straight convert
}

// ---------------- phase A: layer-0 recurrence ----------------
__global__
__attribute__((amdgpu_flat_work_group_size(768, 768), amdgpu_waves_per_eu(3, 3)))
void phaseA_kernel(
    const float* __restrict__ x, const float* __restrict__ meta,
    const float* __restrict__ Wih0, const float* __restrict__ bih0,
    const float* __restrict__ bhh0, const half2_t* __restrict__ WpA,
    float* __restrict__ h0state, __half* __restrict__ h0chunk, int chunk) {
    const int b = blockIdx.x, t = threadIdx.x;
    __shared__ float  s_hf[H_];                      // fp32 h state
    __shared__ __align__(16) __half s_hh[H_];        // f16 copy for the dot
    __shared__ float  s_xg[G_], s_hg[G_];

    // resident weights: row t of W_hh0, 128 k-pairs
    half2_t w[128];
#pragma unroll
    for (int k2 = 0; k2 < 128; k2++) w[k2] = WpA[k2 * G_ + t];

    float wi0[8];
#pragma unroll
    for (int f = 0; f < 8; f++) wi0[f] = Wih0[t * 8 + f];
    const float bi = bih0[t], bh = bhh0[t];
    const float4 mv = reinterpret_cast<const float4*>(meta)[b];

    if (t < H_) {
        float h0 = (chunk == 0) ? 0.f : h0state[b * H_ + t];
        s_hf[t] = h0;
        s_hh[t] = __float2half(h0);
    }
    __syncthreads();

    const float4* xrow = reinterpret_cast<const float4*>(x) + (size_t)b * S_ + (size_t)chunk * CHUNK;

    for (int s = 0; s < CHUNK; s++) {
        float4 xv = xrow[s];  // uniform (broadcast) load
        float a0 = bh, a1 = 0.f, a2 = 0.f, a3 = 0.f;
        const f32x4* hh4 = reinterpret_cast<const f32x4*>(s_hh);  // 32 x b128 broadcast
#pragma unroll
        for (int c = 0; c < 32; c++) {
            f32x4 hv = hh4[c];
            a0 = dot2acc(w[4 * c + 0], h2cast(hv[0]), a0);
            a1 = dot2acc(w[4 * c + 1], h2cast(hv[1]), a1);
            a2 = dot2acc(w[4 * c + 2], h2cast(hv[2]), a2);
            a3 = dot2acc(w[4 * c + 3], h2cast(hv[3]), a3);
        }
        float hg = (a0 + a1) + (a2 + a3);
        float xg = bi + xv.x * wi0[0] + xv.y * wi0[1] + xv.z * wi0[2] + xv.w * wi0[3]
                      + mv.x * wi0[4] + mv.y * wi0[5] + mv.z * wi0[6] + mv.w * wi0[7];
        s_xg[t] = xg;
        s_hg[t] = hg;
        __syncthreads();
        if (t < H_) {
            float r  = sigf(s_xg[t] + s_hg[t]);
            float z  = sigf(s_xg[t + H_] + s_hg[t + H_]);
            float n  = tanh_(s_xg[t + 2 * H_] + r * s_hg[t + 2 * H_]);
            float hn = (1.f - z) * n + z * s_hf[t];
            s_hf[t] = hn;
            __half hh = __float2half(hn);
            s_hh[t] = hh;
            h0chunk[((size_t)(s * B_ + b)) * H_ + t] = hh;  // [s][b][j]
        }
        __syncthreads();
    }
    if (t < H_) h0state[b * H_ + t] = s_hf[t];
}

// ---------------- phase B: xg1 = h0_chunk @ W_ih1^T + b_ih1 (MFMA f16) ----------------
__global__ __launch_bounds__(256) void phaseB_kernel(
    const _Float16* __restrict__ h0chunk, const _Float16* __restrict__ Wi1f,
    const float* __restrict__ bih1, __half* __restrict__ xg1chunk) {
    __shared__ _Float16 lA[128 * 72];  // 128 rows x 64 K, +8 pad (16B-aligned rows)
    __shared__ _Float16 lB[128 * 72];
    const int tid = threadIdx.x;
    const int m0 = blockIdx.x * 128, n0 = blockIdx.y * 128;
    const int wid = tid >> 6, lane = tid & 63;
    const int lm = lane & 15, q8 = (lane >> 4) * 8;
    const int rm = (wid & 1) * 64, cn = (wid >> 1) * 64;

    f32x4 acc[4][4] = {};

    const _Float16* Ag = h0chunk + (size_t)m0 * H_;
    const _Float16* Bg = Wi1f + (size_t)n0 * H_;

    for (int ks = 0; ks < 4; ks++) {  // K = 4 x 64
#pragma unroll
        for (int i = 0; i < 4; i++) {
            int lin = i * 256 + tid;  // 1024 chunks of 16B: 128 rows x 8
            int row = lin >> 3, c8 = lin & 7;
            *reinterpret_cast<float4*>(lA + row * 72 + c8 * 8) =
                *reinterpret_cast<const float4*>(Ag + (size_t)row * H_ + ks * 64 + c8 * 8);
            *reinterpret_cast<float4*>(lB + row * 72 + c8 * 8) =
                *reinterpret_cast<const float4*>(Bg + (size_t)row * H_ + ks * 64 + c8 * 8);
        }
        __syncthreads();
#pragma unroll
        for (int kk = 0; kk < 2; kk++) {
            half8 af[4], bf[4];
#pragma unroll
            for (int i = 0; i < 4; i++)
                af[i] = *reinterpret_cast<const half8*>(lA + (rm + i * 16 + lm) * 72 + kk * 32 + q8);
#pragma unroll
            for (int j = 0; j < 4; j++)
                bf[j] = *reinterpret_cast<const half8*>(lB + (cn + j * 16 + lm) * 72 + kk * 32 + q8);
#pragma unroll
            for (int i = 0; i < 4; i++)
#pragma unroll
                for (int j = 0; j < 4; j++)
                    acc[i][j] = __builtin_amdgcn_mfma_f32_16x16x32_f16(af[i], bf[j], acc[i][j], 0, 0, 0);
        }
        __syncthreads();
    }

    // epilogue: D row=(lane>>4)*4+r (M), col=lane&15 (N)
#pragma unroll
    for (int j = 0; j < 4; j++) {
        int n = n0 + cn + j * 16 + lm;
        float bias = bih1[n];
#pragma unroll
        for (int i = 0; i < 4; i++) {
            int mbase = m0 + rm + i * 16 + (lane >> 4) * 4;
#pragma unroll
            for (int r = 0; r < 4; r++) {
                xg1chunk[(size_t)(mbase + r) * G_ + n] = __float2half(acc[i][j][r] + bias);
            }
        }
    }
}

// ---------------- phase C: layer-1 recurrence + final FC ----------------
__global__
__attribute__((amdgpu_flat_work_group_size(768, 768), amdgpu_waves_per_eu(3, 3)))
void phaseC_kernel(
    const __half* __restrict__ xg1chunk, const half2_t* __restrict__ WpC,
    const float* __restrict__ bhh1, const float* __restrict__ fcW,
    const float* __restrict__ fcb, float* __restrict__ h1state,
    float* __restrict__ out, int chunk) {
    const int b = blockIdx.x, t = threadIdx.x;
    __shared__ float  s_hf[H_];
    __shared__ __align__(16) __half s_hh[H_];
    __shared__ float  s_xg[G_], s_hg[G_];

    half2_t w[128];
#pragma unroll
    for (int k2 = 0; k2 < 128; k2++) w[k2] = WpC[k2 * G_ + t];
    const float bh = bhh1[t];

    if (t < H_) {
        float h0 = (chunk == 0) ? 0.f : h1state[b * H_ + t];
        s_hf[t] = h0;
        s_hh[t] = __float2half(h0);
    }
    __syncthreads();

    for (int s = 0; s < CHUNK; s++) {
        float a0 = bh, a1 = 0.f, a2 = 0.f, a3 = 0.f;
        const f32x4* hh4 = reinterpret_cast<const f32x4*>(s_hh);
#pragma unroll
        for (int c = 0; c < 32; c++) {
            f32x4 hv = hh4[c];
            a0 = dot2acc(w[4 * c + 0], h2cast(hv[0]), a0);
            a1 = dot2acc(w[4 * c + 1], h2cast(hv[1]), a1);
            a2 = dot2acc(w[4 * c + 2], h2cast(hv[2]), a2);
            a3 = dot2acc(w[4 * c + 3], h2cast(hv[3]), a3);
        }
        float hg = (a0 + a1) + (a2 + a3);
        float xg = __half2float(xg1chunk[((size_t)(s * B_ + b)) * G_ + t]);  // b_ih1 pre-added
        s_xg[t] = xg;
        s_hg[t] = hg;
        __syncthreads();
        if (t < H_) {
            float r  = sigf(s_xg[t] + s_hg[t]);
            float z  = sigf(s_xg[t + H_] + s_hg[t + H_]);
            float n  = tanh_(s_xg[t + 2 * H_] + r * s_hg[t + 2 * H_]);
            float hn = (1.f - z) * n + z * s_hf[t];
            s_hf[t] = hn;
            s_hh[t] = __float2half(hn);
        }
        __syncthreads();
    }
    if (t < H_) h1state[b * H_ + t] = s_hf[t];

    if (chunk == NCHUNK - 1) {
        if (t < H_) s_xg[t] = s_hf[t] * fcW[t];
        __syncthreads();
        if (t < 32) {
            float a = 0.f;
            for (int j = t; j < H_; j += 32) a += s_xg[j];
            s_hg[t] = a;
        }
        __syncthreads();
        if (t == 0) {
            float a = fcb[0];
            for (int j = 0; j < 32; j++) a += s_hg[j];
            out[b] = a;
        }
    }
}

extern "C" void kernel_launch(void* const* d_in, const int* in_sizes, int n_in,
                              void* d_out, int out_size, void* d_ws, size_t ws_size,
                              hipStream_t stream) {
    const float* x    = (const float*)d_in[0];
    const float* meta = (const float*)d_in[1];
    const float* Wih0 = (const float*)d_in[2];
    const float* Whh0 = (const float*)d_in[3];
    const float* bih0 = (const float*)d_in[4];
    const float* bhh0 = (const float*)d_in[5];
    const float* Wih1 = (const float*)d_in[6];
    const float* Whh1 = (const float*)d_in[7];
    const float* bih1 = (const float*)d_in[8];
    const float* bhh1 = (const float*)d_in[9];
    const float* fcW  = (const float*)d_in[10];
    const float* fcb  = (const float*)d_in[11];
    float* out = (float*)d_out;

    char* ws = (char*)d_ws;
    __half2* WpA     = (__half2*)(ws + 0);
    __half*  Wi1f    = (__half*)(ws + 393216);
    __half2* WpC     = (__half2*)(ws + 786432);
    float*   h0state = (float*)(ws + 1179648);
    float*   h1state = (float*)(ws + 1441792);
    __half*  h0chunk = (__half*)(ws + 1703936);
    __half*  xg1chunk= (__half*)(ws + 18481152);

    prep_kernel<<<768, 256, 0, stream>>>(Whh0, Wih1, Whh1, WpA, Wi1f, WpC);

    for (int c = 0; c < NCHUNK; c++) {
        phaseA_kernel<<<256, 768, 0, stream>>>(x, meta, Wih0, bih0, bhh0,
                                               (const half2_t*)WpA, h0state, h0chunk, c);
        phaseB_kernel<<<dim3(256, 6), 256, 0, stream>>>(
            (const _Float16*)h0chunk, (const _Float16*)Wi1f, bih1, xg1chunk);
        phaseC_kernel<<<256, 768, 0, stream>>>(xg1chunk, (const half2_t*)WpC, bhh1, fcW, fcb,
                                               h1state, out, c);
    }
}